// Round 12
// baseline (78.166 us; speedup 1.0000x reference)
//
#include <hip/hip_runtime.h>
#include <hip/hip_bf16.h>
#include <stdint.h>

#define K_DIM 128
#define N_X   8192      // columns of x (the "n" / M dimension)
#define N_WO  8192      // 64*128 flattened (w,o) -> GEMM N dimension
#define OUT_TOTAL (8192UL * 64UL * 128UL)
#define CHUNKS_PER_PANEL 131072   // (8192/16 tiles) * 4 ksteps * 64 lanes

typedef __attribute__((ext_vector_type(8))) short short8;   // 8 bf16 = 4 VGPR
typedef __attribute__((ext_vector_type(4))) float f32x4;

__device__ inline unsigned short f2bf(float f) {
    union { float f; unsigned u; } v; v.f = f;
    unsigned u = v.u;
    u += 0x7fffu + ((u >> 16) & 1u);   // round-to-nearest-even
    return (unsigned short)(u >> 16);
}

// Transpose+convert W[128][8192] f32 (k-major, inner contiguous) into MFMA
// fragment-linear bf16 blocks. Chunk cc = ((t*4 + ks)*64 + l), elem j:
//   W[ks*32 + (l>>4)*8 + j][t*16 + (l&15)]
__global__ __launch_bounds__(256) void prep_w(const float* __restrict__ W,
                                              uint4* __restrict__ Q) {
    int cc = blockIdx.x * 256 + threadIdx.x;   // 0 .. 131071
    int l  = cc & 63;
    int ks = (cc >> 6) & 3;
    int t  = cc >> 8;
    int m  = t * 16 + (l & 15);
    int k0 = ks * 32 + ((l >> 4) << 3);
    const float* p = W + (size_t)k0 * N_X + m;
    unsigned short h[8];
#pragma unroll
    for (int j = 0; j < 8; ++j) h[j] = f2bf(p[(size_t)j * N_X]);
    uint4 q;
    q.x = (unsigned)h[0] | ((unsigned)h[1] << 16);
    q.y = (unsigned)h[2] | ((unsigned)h[3] << 16);
    q.z = (unsigned)h[4] | ((unsigned)h[5] << 16);
    q.w = (unsigned)h[6] | ((unsigned)h[7] << 16);
    Q[cc] = q;
}

// Row-slab sweep GEMM (r5 structure — the best measured: 65.2 µs).
// Block = 32 output rows (n) x ALL 8192 wo, 512 threads = 8 waves; wave w
// covers wo-tiles {it*32 + w*4 .. +3} per iteration, 16 iterations.
// x-fragments converted INLINE from f32 once per block (removes half the
// serial prep); W streams from the bf16 fragment panel (L2/L3-resident).
// No LDS, no barriers: stores flow continuously. Normal (cached) stores —
// nt regressed twice (r2, r9): partial-line writes need L2 assembly.
// Operand-SWAPPED mfma: acc = mfma(Wfrag, xfrag) => D[wo][n]; lane holds 4
// consecutive wo at one n -> contiguous dwordx4 stores.
__global__ __launch_bounds__(512, 2) void gemm_sweep(const float* __restrict__ x,
                                                     const short8* __restrict__ B,
                                                     const float* __restrict__ bias,
                                                     float* __restrict__ out) {
    int bid = blockIdx.x;
    // bijective XCD swizzle (256 % 8 == 0): 32 consecutive slabs per XCD
    int swz = (bid & 7) * 32 + (bid >> 3);
    int n0  = swz * 32;

    int tid  = threadIdx.x;
    int lane = tid & 63;
    int w    = tid >> 6;               // 0..7
    int cl = lane & 15, rg = (lane >> 4) << 2;

    // x fragments for this block's 2 row-tiles, all 4 K-steps: convert from
    // raw f32 (same element mapping prep_w uses). Once per block.
    short8 xf[2][4];
#pragma unroll
    for (int i = 0; i < 2; ++i) {
        int m = (swz * 2 + i) * 16 + cl;
#pragma unroll
        for (int ks = 0; ks < 4; ++ks) {
            int k0 = ks * 32 + ((lane >> 4) << 3);
            const float* p = x + (size_t)k0 * N_X + m;
            unsigned short h[8];
#pragma unroll
            for (int j = 0; j < 8; ++j) h[j] = f2bf(p[(size_t)j * N_X]);
            union { uint4 q; short8 s; } u;
            u.q.x = (unsigned)h[0] | ((unsigned)h[1] << 16);
            u.q.y = (unsigned)h[2] | ((unsigned)h[3] << 16);
            u.q.z = (unsigned)h[4] | ((unsigned)h[5] << 16);
            u.q.w = (unsigned)h[6] | ((unsigned)h[7] << 16);
            xf[i][ks] = u.s;
        }
    }

    // bias: (tj*16+rg) mod 128 is iteration-invariant per (w,j) since
    // it*32 % 8 == 0 -> hoist 4 premultiplied float4s into registers.
    f32x4 bvs[4];
#pragma unroll
    for (int j = 0; j < 4; ++j) {
        const f32x4 bv = *(const f32x4*)(bias + ((((w * 4 + j) & 7) << 4) + rg));
        bvs[j].x = 128.0f * bv.x;  bvs[j].y = 128.0f * bv.y;
        bvs[j].z = 128.0f * bv.z;  bvs[j].w = 128.0f * bv.w;
    }

    float* out0 = out + (size_t)n0 * N_WO;
    float* out1 = out0 + 16 * N_WO;

#pragma unroll 2
    for (int it = 0; it < 16; ++it) {
        int tj0 = it * 32 + w * 4;     // this wave's 4 wo-tiles this iteration
        short8 wf[4][4];
#pragma unroll
        for (int j = 0; j < 4; ++j)
#pragma unroll
            for (int ks = 0; ks < 4; ++ks)
                wf[j][ks] = B[(size_t)((tj0 + j) * 4 + ks) * 64 + lane];

        f32x4 acc[2][4] = {};
#pragma unroll
        for (int ks = 0; ks < 4; ++ks)
#pragma unroll
            for (int i = 0; i < 2; ++i)
#pragma unroll
                for (int j = 0; j < 4; ++j)
                    acc[i][j] = __builtin_amdgcn_mfma_f32_16x16x32_bf16(
                        wf[j][ks], xf[i][ks], acc[i][j], 0, 0, 0); // D[wo][n]

        // stores: col(lane&15)=n within tile i, row((lane>>4)*4+reg)=wo
        float* po0 = out0 + (size_t)cl * N_WO;
        float* po1 = out1 + (size_t)cl * N_WO;
#pragma unroll
        for (int j = 0; j < 4; ++j) {
            int wo = (tj0 + j) * 16 + rg;
            f32x4 v0 = acc[0][j], v1 = acc[1][j];
            v0.x += bvs[j].x; v0.y += bvs[j].y; v0.z += bvs[j].z; v0.w += bvs[j].w;
            v1.x += bvs[j].x; v1.y += bvs[j].y; v1.z += bvs[j].z; v1.w += bvs[j].w;
            *(f32x4*)(po0 + wo) = v0;
            *(f32x4*)(po1 + wo) = v1;
        }
    }
}

// Correctness fallback if d_ws is too small for the transposed panel.
__global__ __launch_bounds__(256) void naive_kernel(const float* __restrict__ x,
                                                    const float* __restrict__ wgt,
                                                    const float* __restrict__ bias,
                                                    float* __restrict__ out) {
    size_t idx = (size_t)blockIdx.x * 256 + threadIdx.x;
    if (idx >= OUT_TOTAL) return;
    int n    = (int)(idx >> 13);
    int ncol = (int)(idx & 8191);
    float s = 0.f;
    for (int i = 0; i < K_DIM; ++i)
        s += x[(size_t)i * N_X + n] * wgt[(size_t)i * N_WO + ncol];
    out[idx] = s + 128.0f * bias[ncol & 127];
}

extern "C" void kernel_launch(void* const* d_in, const int* in_sizes, int n_in,
                              void* d_out, int out_size, void* d_ws, size_t ws_size,
                              hipStream_t stream) {
    const float* x    = (const float*)d_in[0];   // [128][8192]
    const float* wgt  = (const float*)d_in[1];   // [128][64*128]
    const float* bias = (const float*)d_in[2];   // [128]
    float* out = (float*)d_out;

    if (ws_size >= 2u * 1024u * 1024u) {
        uint4* wsB = (uint4*)d_ws;                    // 2 MiB: W frag bf16
        prep_w<<<512, 256, 0, stream>>>(wgt, wsB);
        gemm_sweep<<<256, 512, 0, stream>>>(x, (const short8*)wsB, bias, out);
    } else {
        naive_kernel<<<(unsigned)((OUT_TOTAL + 255) / 256), 256, 0, stream>>>(
            x, wgt, bias, out);
    }
}

// Round 13
// 63.073 us; speedup vs baseline: 1.2393x; 1.2393x over previous
//
#include <hip/hip_runtime.h>
#include <hip/hip_bf16.h>
#include <stdint.h>

#define K_DIM 128
#define N_X   8192      // columns of x (the "n" / M dimension)
#define N_WO  8192      // 64*128 flattened (w,o) -> GEMM N dimension
#define OUT_TOTAL (8192UL * 64UL * 128UL)
#define CHUNKS_PER_PANEL 131072   // (8192/16 tiles) * 4 ksteps * 64 lanes

typedef __attribute__((ext_vector_type(8))) short short8;   // 8 bf16 = 4 VGPR
typedef __attribute__((ext_vector_type(4))) float f32x4;

__device__ inline unsigned short f2bf(float f) {
    union { float f; unsigned u; } v; v.f = f;
    unsigned u = v.u;
    u += 0x7fffu + ((u >> 16) & 1u);   // round-to-nearest-even
    return (unsigned short)(u >> 16);
}

// Transpose+convert BOTH panels P[128][8192] f32 (k-major, inner contiguous)
// into MFMA fragment-linear bf16 blocks. Chunk cc = ((t*4 + ks)*64 + l):
//   elem j (0..7): P[ks*32 + (l>>4)*8 + j][t*16 + (l&15)]
__global__ __launch_bounds__(256) void prep_frag2(const float* __restrict__ X,
                                                  const float* __restrict__ W,
                                                  uint4* __restrict__ Q) {
    int c  = blockIdx.x * 256 + threadIdx.x;   // 0 .. 262143
    int cc = c & (CHUNKS_PER_PANEL - 1);
    const float* P = (c >= CHUNKS_PER_PANEL) ? W : X;
    int l  = cc & 63;
    int ks = (cc >> 6) & 3;
    int t  = cc >> 8;
    int m  = t * 16 + (l & 15);
    int k0 = ks * 32 + ((l >> 4) << 3);
    const float* p = P + (size_t)k0 * N_X + m;
    unsigned short h[8];
#pragma unroll
    for (int j = 0; j < 8; ++j) h[j] = f2bf(p[(size_t)j * N_X]);
    uint4 q;
    q.x = (unsigned)h[0] | ((unsigned)h[1] << 16);
    q.y = (unsigned)h[2] | ((unsigned)h[3] << 16);
    q.z = (unsigned)h[4] | ((unsigned)h[5] << 16);
    q.w = (unsigned)h[6] | ((unsigned)h[7] << 16);
    Q[c] = q;
}

// Row-slab sweep GEMM: block = 32 output rows (n) x ALL 8192 wo.
// Output region out[n0:n0+32][*] is CONTIGUOUS 1 MiB, swept monotonically in
// 16 iterations -> stores flow continuously (no phases, no barriers, no LDS),
// and each CU keeps only 32 linear HBM write streams (page-friendly).
// x-frags (8 KiB) stay in registers for the whole kernel; W-frags stream from
// L2 (panel is 2 MiB, L2-resident per XCD). Operand-SWAPPED mfma:
//   acc = mfma(Wfrag, xfrag) => D[wo][n]; lane = 4 consecutive wo at one n.
__global__ __launch_bounds__(512, 2) void gemm_sweep(const short8* __restrict__ A,
                                                     const short8* __restrict__ B,
                                                     const float* __restrict__ bias,
                                                     float* __restrict__ out) {
    int bid = blockIdx.x;
    // bijective XCD swizzle (256 % 8 == 0): 32 consecutive slabs per XCD
    int swz = (bid & 7) * 32 + (bid >> 3);
    int n0  = swz * 32;

    int tid  = threadIdx.x;
    int lane = tid & 63;
    int w    = tid >> 6;               // 0..7

    // x fragments for this block's 2 row-tiles, all 4 K-steps (held in VGPRs)
    int tA = swz * 2;
    short8 xf[2][4];
#pragma unroll
    for (int i = 0; i < 2; ++i)
#pragma unroll
        for (int ks = 0; ks < 4; ++ks)
            xf[i][ks] = A[((tA + i) * 4 + ks) * 64 + lane];

    int cl = lane & 15, rg = (lane >> 4) << 2;

    // bias: (tj*16+rg) mod 128 is iteration-invariant per (w,j) since
    // it*32 % 8 == 0 -> hoist 4 premultiplied float4s into registers.
    f32x4 bvs[4];
#pragma unroll
    for (int j = 0; j < 4; ++j) {
        const f32x4 bv = *(const f32x4*)(bias + ((((w * 4 + j) & 7) << 4) + rg));
        bvs[j].x = 128.0f * bv.x;  bvs[j].y = 128.0f * bv.y;
        bvs[j].z = 128.0f * bv.z;  bvs[j].w = 128.0f * bv.w;
    }

    float* out0 = out + (size_t)n0 * N_WO;
    float* out1 = out0 + 16 * N_WO;

#pragma unroll 2
    for (int it = 0; it < 16; ++it) {
        int tj0 = it * 32 + w * 4;     // this wave's 4 wo-tiles this iteration
        short8 wf[4][4];
#pragma unroll
        for (int j = 0; j < 4; ++j)
#pragma unroll
            for (int ks = 0; ks < 4; ++ks)
                wf[j][ks] = B[((tj0 + j) * 4 + ks) * 64 + lane];

        f32x4 acc[2][4] = {};
#pragma unroll
        for (int ks = 0; ks < 4; ++ks)
#pragma unroll
            for (int i = 0; i < 2; ++i)
#pragma unroll
                for (int j = 0; j < 4; ++j)
                    acc[i][j] = __builtin_amdgcn_mfma_f32_16x16x32_bf16(
                        wf[j][ks], xf[i][ks], acc[i][j], 0, 0, 0); // D[wo][n]

        // stores: col(lane&15)=n within tile i, row((lane>>4)*4+reg)=wo
        float* po0 = out0 + (size_t)cl * N_WO;
        float* po1 = out1 + (size_t)cl * N_WO;
#pragma unroll
        for (int j = 0; j < 4; ++j) {
            int wo = (tj0 + j) * 16 + rg;
            f32x4 v0 = acc[0][j], v1 = acc[1][j];
            v0.x += bvs[j].x; v0.y += bvs[j].y; v0.z += bvs[j].z; v0.w += bvs[j].w;
            v1.x += bvs[j].x; v1.y += bvs[j].y; v1.z += bvs[j].z; v1.w += bvs[j].w;
            *(f32x4*)(po0 + wo) = v0;
            *(f32x4*)(po1 + wo) = v1;
        }
    }
}

// Correctness fallback if d_ws is too small for the transposed panels.
__global__ __launch_bounds__(256) void naive_kernel(const float* __restrict__ x,
                                                    const float* __restrict__ wgt,
                                                    const float* __restrict__ bias,
                                                    float* __restrict__ out) {
    size_t idx = (size_t)blockIdx.x * 256 + threadIdx.x;
    if (idx >= OUT_TOTAL) return;
    int n    = (int)(idx >> 13);
    int ncol = (int)(idx & 8191);
    float s = 0.f;
    for (int i = 0; i < K_DIM; ++i)
        s += x[(size_t)i * N_X + n] * wgt[(size_t)i * N_WO + ncol];
    out[idx] = s + 128.0f * bias[ncol & 127];
}

extern "C" void kernel_launch(void* const* d_in, const int* in_sizes, int n_in,
                              void* d_out, int out_size, void* d_ws, size_t ws_size,
                              hipStream_t stream) {
    const float* x    = (const float*)d_in[0];   // [128][8192]
    const float* wgt  = (const float*)d_in[1];   // [128][64*128]
    const float* bias = (const float*)d_in[2];   // [128]
    float* out = (float*)d_out;

    if (ws_size >= 4u * 1024u * 1024u) {
        uint4* wsA = (uint4*)d_ws;                    // 2 MiB: x^T frag bf16
        uint4* wsB = wsA + CHUNKS_PER_PANEL;          // 2 MiB: W   frag bf16
        prep_frag2<<<1024, 256, 0, stream>>>(x, wgt, wsA);
        gemm_sweep<<<256, 512, 0, stream>>>((const short8*)wsA,
                                            (const short8*)wsB, bias, out);
    } else {
        naive_kernel<<<(unsigned)((OUT_TOTAL + 255) / 256), 256, 0, stream>>>(
            x, wgt, bias, out);
    }
}